// Round 9
// baseline (232.083 us; speedup 1.0000x reference)
//
#include <hip/hip_runtime.h>
#include <hip/hip_bf16.h>

// Problem constants
#define Bn 2
#define Tdim 2048
#define Ddim 1024
#define Hn 16
#define HD 64

typedef unsigned short u16;
typedef unsigned int u32;
typedef __attribute__((ext_vector_type(8))) __bf16 bf16x8;
typedef __attribute__((ext_vector_type(4))) float f32x4;
typedef __attribute__((ext_vector_type(16))) float f32x16;
typedef __attribute__((ext_vector_type(4))) u32 u32x4;

struct alignas(8) U16x4 { u16 x, y, z, w; };
struct alignas(16) U16x8 { u16 s[8]; };

#define OSZ (32u * 2048u * 64u)  // one split-half of partial O

__device__ __forceinline__ u16 f2bf(float f) {
  union { float f; u32 i; } v; v.f = f;
  u32 x = v.i;
  u32 r = (x + 0x7fffu + ((x >> 16) & 1u)) >> 16;
  return (u16)r;
}
__device__ __forceinline__ float bf2f(u16 u) {
  union { u32 i; float f; } v; v.i = ((u32)u) << 16; return v.f;
}
__device__ __forceinline__ u32 fbits(float f) {
  union { float f; u32 i; } v; v.f = f; return v.i;
}

// async global->LDS, 16B per lane; LDS dest = wave-uniform base + lane*16
__device__ __forceinline__ void cp16(const u16* g, u16* l) {
  __builtin_amdgcn_global_load_lds(
      (const __attribute__((address_space(1))) u32*)g,
      (__attribute__((address_space(3))) u32*)l, 16, 0, 0);
}

__device__ __forceinline__ f32x4 mfma16(bf16x8 a, bf16x8 b, f32x4 c) {
  return __builtin_amdgcn_mfma_f32_16x16x32_bf16(a, b, c, 0, 0, 0);
}
__device__ __forceinline__ f32x16 mfma32(bf16x8 a, bf16x8 b, f32x16 c) {
  return __builtin_amdgcn_mfma_f32_32x32x16_bf16(a, b, c, 0, 0, 0);
}

// ---------------- X f32 -> bf16 convert ----------------
__global__ __launch_bounds__(256) void convert_x(const float* __restrict__ src,
                                                 u16* __restrict__ dst) {
  const int i = (blockIdx.x * 256 + threadIdx.x) * 8;
  u16 t[8];
#pragma unroll
  for (int j = 0; j < 8; j++) t[j] = f2bf(src[i + j]);
  *(bf16x8*)&dst[i] = *(const bf16x8*)t;
}

// ---------------- weight transpose + f32->bf16 convert (4x 1024x1024, fused) ----------------
__global__ __launch_bounds__(256) void transpose_k(
    const float* __restrict__ s0, const float* __restrict__ s1,
    const float* __restrict__ s2, const float* __restrict__ s3,
    u16* __restrict__ dst) {
  const float* src = (blockIdx.z == 0) ? s0 : (blockIdx.z == 1) ? s1
                   : (blockIdx.z == 2) ? s2 : s3;
  u16* d = dst + (size_t)blockIdx.z * Ddim * Ddim;
  __shared__ u16 tile[32][33];
  const int tx = threadIdx.x, ty = threadIdx.y;
  const int x = blockIdx.x * 32 + tx;
  const int y0 = blockIdx.y * 32;
#pragma unroll
  for (int j = 0; j < 32; j += 8) tile[ty + j][tx] = f2bf(src[(size_t)(y0 + ty + j) * Ddim + x]);
  __syncthreads();
  const int xo = blockIdx.y * 32 + tx;
  const int yo0 = blockIdx.x * 32;
#pragma unroll
  for (int j = 0; j < 32; j += 8) d[(size_t)(yo0 + ty + j) * Ddim + xo] = tile[tx][ty + j];
}

// ---------------- fused QKV projection GEMM (global_load_lds staging) ----------------
__global__ __launch_bounds__(256, 2) void gemm_qkv(
    const u16* __restrict__ Xb, const u16* __restrict__ WT,
    const float* __restrict__ bq, const float* __restrict__ bk, const float* __restrict__ bv,
    u16* __restrict__ Q, u16* __restrict__ K, u16* __restrict__ Vt) {
  const int z = blockIdx.z;
  const u16* Wt = WT + (size_t)z * Ddim * Ddim;
  const float* bias = (z == 0) ? bq : (z == 1) ? bk : bv;
  u16* QK = (z == 0) ? Q : K;

  __shared__ alignas(16) u16 Alds[128 * 32];
  __shared__ alignas(16) u16 Blds[128 * 32];
  const int tid = threadIdx.x;
  const int w = tid >> 6, lane = tid & 63, ln = lane & 15, quad = lane >> 4;
  const int wm = (w >> 1) * 64, wn = (w & 1) * 64;
  const int tm = blockIdx.x * 128, tn = blockIdx.y * 128;

  f32x4 acc[4][4] = {};

  const int srow = tid >> 2, scol = (tid & 3) * 8;
  const u16* ag = Xb + (size_t)(tm + srow) * Ddim + scol;
  const u16* ag2 = ag + (size_t)64 * Ddim;
  const u16* bg = Wt + (size_t)(tn + srow) * Ddim + scol;
  const u16* bg2 = bg + (size_t)64 * Ddim;
  u16* al = &Alds[w * 512];
  u16* al2 = &Alds[2048 + w * 512];
  u16* bl = &Blds[w * 512];
  u16* bl2 = &Blds[2048 + w * 512];

  for (int k0 = 0; k0 < Ddim; k0 += 32) {
    __syncthreads();
    cp16(ag + k0, al);
    cp16(ag2 + k0, al2);
    cp16(bg + k0, bl);
    cp16(bg2 + k0, bl2);
    __syncthreads();
    bf16x8 af[4], bfr[4];
#pragma unroll
    for (int i = 0; i < 4; i++)
      af[i] = *(const bf16x8*)&Alds[(wm + i * 16 + ln) * 32 + quad * 8];
#pragma unroll
    for (int i = 0; i < 4; i++)
      bfr[i] = *(const bf16x8*)&Blds[(wn + i * 16 + ln) * 32 + quad * 8];
#pragma unroll
    for (int mi = 0; mi < 4; mi++)
#pragma unroll
      for (int ni = 0; ni < 4; ni++)
        acc[mi][ni] = mfma16(af[mi], bfr[ni], acc[mi][ni]);
  }

#pragma unroll
  for (int mi = 0; mi < 4; mi++) {
#pragma unroll
    for (int ni = 0; ni < 4; ni++) {
      const int gm0 = tm + wm + mi * 16 + quad * 4;
      const int gn = tn + wn + ni * 16 + ln;
      const float bv_ = bias[gn];
      const int hh = gn >> 6, dd = gn & 63;
      const int b0 = gm0 >> 11, t0 = gm0 & 2047;
      if (z < 2) {
        u16* p = QK + (((size_t)(b0 * Hn + hh) * Tdim) + t0) * HD + dd;
#pragma unroll
        for (int r = 0; r < 4; r++) p[r * HD] = f2bf(acc[mi][ni][r] + bv_);
      } else {
        U16x4 pk;
        pk.x = f2bf(acc[mi][ni][0] + bv_);
        pk.y = f2bf(acc[mi][ni][1] + bv_);
        pk.z = f2bf(acc[mi][ni][2] + bv_);
        pk.w = f2bf(acc[mi][ni][3] + bv_);
        *(U16x4*)&Vt[((size_t)(b0 * Hn + hh) * HD + dd) * Tdim + t0] = pk;
      }
    }
  }
}

// ---------------- flash attention v6: register diet for 4 blocks/CU ----------------
// grid (32, 32): qb = 15-(bx>>1) heavy-first, s = bx&1 split-K half.
// Inner loop processes key-halves of 64 so only st[2] (32 acc) is live;
// P fragments consumed into PV immediately. No reg prefetch (rely on
// inter-block overlap at 4 blocks/CU).
#define KSTR 68
#define VSTR 132
#define L2E 1.44269504088896f
__global__ __launch_bounds__(256, 4) void attn_k(
    const u16* __restrict__ Q, const u16* __restrict__ K, const u16* __restrict__ Vt,
    u16* __restrict__ Op, float* __restrict__ lp) {
  __shared__ alignas(16) u16 Klds[128 * KSTR];
  __shared__ alignas(16) u16 Vtlds[64 * VSTR];

  const int bx = blockIdx.x;
  const int qb = 15 - (bx >> 1);
  const int s = bx & 1;
  const int bh = blockIdx.y;
  const int q0 = qb * 128;
  const int tid = threadIdx.x;
  const int w = tid >> 6, lane = tid & 63;
  const int qi = lane & 31, hf = lane >> 5;

  const u16* Qh = Q + (size_t)bh * Tdim * HD;
  const u16* Kh = K + (size_t)bh * Tdim * HD;
  const u16* Vh = Vt + (size_t)bh * HD * Tdim;
  const float slope = exp2f(-0.5f * (float)((bh & 15) + 1));

  const int nkt = qb + 1;
  const int h0 = (nkt + 1) >> 1;
  const int kt0 = s ? h0 : 0;
  const int kt1 = s ? nkt : h0;

  const int tg = q0 + w * 32 + qi;
  const float sl2 = slope * L2E;
  const float c1 = 0.125f * L2E;
  const float tt2 = (slope * (float)tg + 3.0f) * L2E;
  const float f4hf = (float)(4 * hf);
  float sg8[4], slm[4];
#pragma unroll
  for (int g = 0; g < 4; g++) sg8[g] = sl2 * (float)(8 * g);
#pragma unroll
  for (int m = 0; m < 4; m++) slm[m] = sl2 * (float)m;

  bf16x8 qf[4];
#pragma unroll
  for (int kc = 0; kc < 4; kc++)
    qf[kc] = *(const bf16x8*)&Qh[(size_t)tg * HD + kc * 16 + hf * 8];

  float lsum = 0.f;
  f32x16 oacc[2] = {};

  for (int kt = kt0; kt < kt1; kt++) {
    const int kb = kt * 128;
    __syncthreads();
    {
      bf16x8 kr[4], vr[4];
#pragma unroll
      for (int c = 0; c < 4; c++) {
        const int e = c * 2048 + tid * 8;
        kr[c] = *(const bf16x8*)&Kh[(size_t)(kb + (e >> 6)) * HD + (e & 63)];
        vr[c] = *(const bf16x8*)&Vh[(size_t)(e >> 7) * Tdim + kb + (e & 127)];
      }
#pragma unroll
      for (int c = 0; c < 4; c++) {
        const int e = c * 2048 + tid * 8;
        *(bf16x8*)&Klds[(e >> 6) * KSTR + (e & 63)] = kr[c];
        *(bf16x8*)&Vtlds[(e >> 7) * VSTR + (e & 127)] = vr[c];
      }
    }
    __syncthreads();

    const bool diag = (kt == nkt - 1);
    const float fkb = (float)kb + f4hf;

#pragma unroll
    for (int half = 0; half < 2; half++) {
      // S^T = K Q^T for 64 keys (2 tiles of 32)
      f32x16 st[2] = {};
#pragma unroll
      for (int kc = 0; kc < 4; kc++) {
#pragma unroll
        for (int j = 0; j < 2; j++) {
          bf16x8 kf = *(const bf16x8*)&Klds[(half * 64 + j * 32 + qi) * KSTR + kc * 16 + hf * 8];
          st[j] = mfma32(kf, qf[kc], st[j]);
        }
      }
#pragma unroll
      for (int j = 0; j < 2; j++) {
        const int ni = half * 2 + j;
        const float cni = __builtin_fmaf(sl2, fkb + (float)(32 * ni), -tt2);
        u32 pu[16];
        if (!diag) {
#pragma unroll
          for (int ri = 0; ri < 16; ri++) {
            const float e = __builtin_fmaf(st[j][ri], c1, cni + sg8[ri >> 2] + slm[ri & 3]);
            const float p = __builtin_amdgcn_exp2f(e);
            lsum += p;
            pu[ri] = fbits(p) + 0x8000u;
          }
        } else {
#pragma unroll
          for (int ri = 0; ri < 16; ri++) {
            const int n = kb + ni * 32 + (ri & 3) + 8 * (ri >> 2) + 4 * hf;
            const float e = __builtin_fmaf(st[j][ri], c1, cni + sg8[ri >> 2] + slm[ri & 3]);
            float p = __builtin_amdgcn_exp2f(e);
            if (n > tg) p = 0.f;
            lsum += p;
            pu[ri] = fbits(p) + 0x8000u;
          }
        }
        u32 pk[4][2];
#pragma unroll
        for (int g = 0; g < 4; g++) {
          pk[g][0] = __builtin_amdgcn_perm(pu[g * 4 + 1], pu[g * 4 + 0], 0x07060302u);
          pk[g][1] = __builtin_amdgcn_perm(pu[g * 4 + 3], pu[g * 4 + 2], 0x07060302u);
        }
#pragma unroll
        for (int a = 0; a < 2; a++) {
          const u32 snd0 = (hf == 0) ? pk[2 * a + 1][0] : pk[2 * a][0];
          const u32 snd1 = (hf == 0) ? pk[2 * a + 1][1] : pk[2 * a][1];
          const u32 rcv0 = (u32)__shfl_xor((int)snd0, 32);
          const u32 rcv1 = (u32)__shfl_xor((int)snd1, 32);
          u32x4 fr;
          fr.x = (hf == 0) ? pk[2 * a][0] : rcv0;
          fr.y = (hf == 0) ? pk[2 * a][1] : rcv1;
          fr.z = (hf == 0) ? rcv0 : pk[2 * a + 1][0];
          fr.w = (hf == 0) ? rcv1 : pk[2 * a + 1][1];
          const bf16x8 pfrag = *(bf16x8*)&fr;
          const int kf16 = ni * 2 + a;
#pragma unroll
          for (int nd = 0; nd < 2; nd++) {
            bf16x8 vf = *(const bf16x8*)&Vtlds[(nd * 32 + qi) * VSTR + kf16 * 16 + hf * 8];
            oacc[nd] = mfma32(pfrag, vf, oacc[nd]);
          }
        }
      }
    }
  }

  lsum += __shfl_xor(lsum, 32);
  if (hf == 0) lp[(size_t)s * 65536 + bh * Tdim + tg] = lsum;

  u16* Ob = Op + (size_t)s * OSZ + ((size_t)bh * Tdim) * HD;
#pragma unroll
  for (int nd = 0; nd < 2; nd++) {
#pragma unroll
    for (int ri = 0; ri < 16; ri++) {
      const int rq = (ri & 3) + 8 * (ri >> 2) + 4 * hf;
      const int t = q0 + w * 32 + rq;
      Ob[(size_t)t * HD + nd * 32 + qi] = f2bf(oacc[nd][ri]);
    }
  }
}

// ---------------- output projection GEMM with fused merge (f32 out) ----------------
// A-tile staged on the fly from Op0+Op1 with 1/l normalization.
// 64x128 tiles -> grid (64, 8) = 512 blocks.
__global__ __launch_bounds__(256, 4) void gemm_out(
    const u16* __restrict__ Op, const float* __restrict__ lp,
    const u16* __restrict__ WoT, const float* __restrict__ bo,
    float* __restrict__ C) {
  __shared__ alignas(16) u16 Alds[64 * 32];
  __shared__ alignas(16) u16 Blds[128 * 32];
  const int tid = threadIdx.x;
  const int w = tid >> 6, lane = tid & 63, ln = lane & 15, quad = lane >> 4;
  const int wm = (w >> 1) * 32, wn = (w & 1) * 64;
  const int tm = blockIdx.x * 64, tn = blockIdx.y * 128;

  f32x4 acc[2][4] = {};

  const int srow = tid >> 2, scol = (tid & 3) * 8;
  const int arow = tm + srow;
  const int t = arow & 2047, bb = arow >> 11;
  const u16* bg = WoT + (size_t)(tn + srow) * Ddim + scol;
  const u16* bg2 = bg + (size_t)64 * Ddim;
  u16* bl = &Blds[w * 512];
  u16* bl2 = &Blds[2048 + w * 512];

  for (int k0 = 0; k0 < Ddim; k0 += 32) {
    __syncthreads();
    cp16(bg + k0, bl);
    cp16(bg2 + k0, bl2);
    {
      const int col = k0 + scol;
      const int h = col >> 6, d = col & 63;
      const int bh = bb * 16 + h;
      const float l = lp[bh * Tdim + t] + lp[65536 + bh * Tdim + t];
      const float inv = 1.0f / l;
      const size_t off = ((size_t)bh * Tdim + t) * HD + d;
      U16x8 o0 = *(const U16x8*)&Op[off];
      U16x8 o1 = *(const U16x8*)&Op[OSZ + off];
      u16 tmp[8];
#pragma unroll
      for (int j = 0; j < 8; j++)
        tmp[j] = f2bf((bf2f(o0.s[j]) + bf2f(o1.s[j])) * inv);
      *(bf16x8*)&Alds[srow * 32 + scol] = *(const bf16x8*)tmp;
    }
    __syncthreads();
    bf16x8 af[2], bfr[4];
#pragma unroll
    for (int i = 0; i < 2; i++)
      af[i] = *(const bf16x8*)&Alds[(wm + i * 16 + ln) * 32 + quad * 8];
#pragma unroll
    for (int i = 0; i < 4; i++)
      bfr[i] = *(const bf16x8*)&Blds[(wn + i * 16 + ln) * 32 + quad * 8];
#pragma unroll
    for (int mi = 0; mi < 2; mi++)
#pragma unroll
      for (int ni = 0; ni < 4; ni++)
        acc[mi][ni] = mfma16(af[mi], bfr[ni], acc[mi][ni]);
  }

#pragma unroll
  for (int mi = 0; mi < 2; mi++) {
#pragma unroll
    for (int ni = 0; ni < 4; ni++) {
      const int gm0 = tm + wm + mi * 16 + quad * 4;
      const int gn = tn + wn + ni * 16 + ln;
      const float bv_ = bo[gn];
#pragma unroll
      for (int r = 0; r < 4; r++)
        C[(size_t)(gm0 + r) * Ddim + gn] = acc[mi][ni][r] + bv_;
    }
  }
}

extern "C" void kernel_launch(void* const* d_in, const int* in_sizes, int n_in,
                              void* d_out, int out_size, void* d_ws, size_t ws_size,
                              hipStream_t stream) {
  (void)in_sizes; (void)n_in; (void)out_size; (void)ws_size;
  const float* x  = (const float*)d_in[0];
  const float* Wq = (const float*)d_in[1];
  const float* bq = (const float*)d_in[2];
  const float* Wk = (const float*)d_in[3];
  const float* bk = (const float*)d_in[4];
  const float* Wv = (const float*)d_in[5];
  const float* bv = (const float*)d_in[6];
  const float* Wo = (const float*)d_in[7];
  const float* bo = (const float*)d_in[8];

  char* ws = (char*)d_ws;
  const size_t MB = 1024 * 1024;
  u16* WT   = (u16*)(ws + 0 * MB);   // 8MB: WqT, WkT, WvT, WoT (z-major)
  u16* Qb   = (u16*)(ws + 8 * MB);   // 8MB bf16 (B,H,T,64)
  u16* Kb   = (u16*)(ws + 16 * MB);
  u16* Vtb  = (u16*)(ws + 24 * MB);  // 8MB bf16 (B,H,64,T)
  u16* Xb   = (u16*)(ws + 32 * MB);  // 8MB bf16 X
  u16* Opart= (u16*)(ws + 40 * MB);  // 16MB: 2 x (BH,T,64) bf16 partial O
  float* lpart = (float*)(ws + 56 * MB); // 512KB: 2 x (BH,T) f32 partial l
  u16* WoT = WT + (size_t)3 * Ddim * Ddim;

  convert_x<<<dim3(2048), 256, 0, stream>>>(x, Xb);
  transpose_k<<<dim3(32, 32, 4), dim3(32, 8), 0, stream>>>(Wq, Wk, Wv, Wo, WT);

  gemm_qkv<<<dim3(32, 8, 3), 256, 0, stream>>>(Xb, WT, bq, bk, bv, Qb, Kb, Vtb);
  attn_k<<<dim3(32, 32), 256, 0, stream>>>(Qb, Kb, Vtb, Opart, lpart);
  gemm_out<<<dim3(64, 8), 256, 0, stream>>>(Opart, lpart, WoT, bo, (float*)d_out);
}

// Round 10
// 210.209 us; speedup vs baseline: 1.1041x; 1.1041x over previous
//
#include <hip/hip_runtime.h>
#include <hip/hip_bf16.h>

// Problem constants
#define Bn 2
#define Tdim 2048
#define Ddim 1024
#define Hn 16
#define HD 64

typedef unsigned short u16;
typedef unsigned int u32;
typedef __attribute__((ext_vector_type(8))) __bf16 bf16x8;
typedef __attribute__((ext_vector_type(4))) float f32x4;
typedef __attribute__((ext_vector_type(16))) float f32x16;
typedef __attribute__((ext_vector_type(4))) u32 u32x4;

struct alignas(8) U16x4 { u16 x, y, z, w; };
struct alignas(16) U16x8 { u16 s[8]; };

#define OSZ (32u * 2048u * 64u)  // one split-half of partial O

__device__ __forceinline__ u16 f2bf(float f) {
  union { float f; u32 i; } v; v.f = f;
  u32 x = v.i;
  u32 r = (x + 0x7fffu + ((x >> 16) & 1u)) >> 16;
  return (u16)r;
}
__device__ __forceinline__ float bf2f(u16 u) {
  union { u32 i; float f; } v; v.i = ((u32)u) << 16; return v.f;
}
__device__ __forceinline__ u32 fbits(float f) {
  union { float f; u32 i; } v; v.f = f; return v.i;
}

// async global->LDS, 16B per lane; LDS dest = wave-uniform base + lane*16
__device__ __forceinline__ void cp16(const u16* g, u16* l) {
  __builtin_amdgcn_global_load_lds(
      (const __attribute__((address_space(1))) u32*)g,
      (__attribute__((address_space(3))) u32*)l, 16, 0, 0);
}

__device__ __forceinline__ f32x4 mfma16(bf16x8 a, bf16x8 b, f32x4 c) {
  return __builtin_amdgcn_mfma_f32_16x16x32_bf16(a, b, c, 0, 0, 0);
}
__device__ __forceinline__ f32x16 mfma32(bf16x8 a, bf16x8 b, f32x16 c) {
  return __builtin_amdgcn_mfma_f32_32x32x16_bf16(a, b, c, 0, 0, 0);
}

// ---------------- X f32 -> bf16 convert ----------------
__global__ __launch_bounds__(256) void convert_x(const float* __restrict__ src,
                                                 u16* __restrict__ dst) {
  const int i = (blockIdx.x * 256 + threadIdx.x) * 8;
  u16 t[8];
#pragma unroll
  for (int j = 0; j < 8; j++) t[j] = f2bf(src[i + j]);
  *(bf16x8*)&dst[i] = *(const bf16x8*)t;
}

// ---------------- weight transpose + f32->bf16 convert (4x 1024x1024, fused) ----------------
__global__ __launch_bounds__(256) void transpose_k(
    const float* __restrict__ s0, const float* __restrict__ s1,
    const float* __restrict__ s2, const float* __restrict__ s3,
    u16* __restrict__ dst) {
  const float* src = (blockIdx.z == 0) ? s0 : (blockIdx.z == 1) ? s1
                   : (blockIdx.z == 2) ? s2 : s3;
  u16* d = dst + (size_t)blockIdx.z * Ddim * Ddim;
  __shared__ u16 tile[32][33];
  const int tx = threadIdx.x, ty = threadIdx.y;
  const int x = blockIdx.x * 32 + tx;
  const int y0 = blockIdx.y * 32;
#pragma unroll
  for (int j = 0; j < 32; j += 8) tile[ty + j][tx] = f2bf(src[(size_t)(y0 + ty + j) * Ddim + x]);
  __syncthreads();
  const int xo = blockIdx.y * 32 + tx;
  const int yo0 = blockIdx.x * 32;
#pragma unroll
  for (int j = 0; j < 32; j += 8) d[(size_t)(yo0 + ty + j) * Ddim + xo] = tile[tx][ty + j];
}

// ---------------- fused QKV projection GEMM (global_load_lds staging) ----------------
__global__ __launch_bounds__(256, 2) void gemm_qkv(
    const u16* __restrict__ Xb, const u16* __restrict__ WT,
    const float* __restrict__ bq, const float* __restrict__ bk, const float* __restrict__ bv,
    u16* __restrict__ Q, u16* __restrict__ K, u16* __restrict__ Vt) {
  const int z = blockIdx.z;
  const u16* Wt = WT + (size_t)z * Ddim * Ddim;
  const float* bias = (z == 0) ? bq : (z == 1) ? bk : bv;
  u16* QK = (z == 0) ? Q : K;

  __shared__ alignas(16) u16 Alds[128 * 32];
  __shared__ alignas(16) u16 Blds[128 * 32];
  const int tid = threadIdx.x;
  const int w = tid >> 6, lane = tid & 63, ln = lane & 15, quad = lane >> 4;
  const int wm = (w >> 1) * 64, wn = (w & 1) * 64;
  const int tm = blockIdx.x * 128, tn = blockIdx.y * 128;

  f32x4 acc[4][4] = {};

  const int srow = tid >> 2, scol = (tid & 3) * 8;
  const u16* ag = Xb + (size_t)(tm + srow) * Ddim + scol;
  const u16* ag2 = ag + (size_t)64 * Ddim;
  const u16* bg = Wt + (size_t)(tn + srow) * Ddim + scol;
  const u16* bg2 = bg + (size_t)64 * Ddim;
  u16* al = &Alds[w * 512];
  u16* al2 = &Alds[2048 + w * 512];
  u16* bl = &Blds[w * 512];
  u16* bl2 = &Blds[2048 + w * 512];

  for (int k0 = 0; k0 < Ddim; k0 += 32) {
    __syncthreads();
    cp16(ag + k0, al);
    cp16(ag2 + k0, al2);
    cp16(bg + k0, bl);
    cp16(bg2 + k0, bl2);
    __syncthreads();
    bf16x8 af[4], bfr[4];
#pragma unroll
    for (int i = 0; i < 4; i++)
      af[i] = *(const bf16x8*)&Alds[(wm + i * 16 + ln) * 32 + quad * 8];
#pragma unroll
    for (int i = 0; i < 4; i++)
      bfr[i] = *(const bf16x8*)&Blds[(wn + i * 16 + ln) * 32 + quad * 8];
#pragma unroll
    for (int mi = 0; mi < 4; mi++)
#pragma unroll
      for (int ni = 0; ni < 4; ni++)
        acc[mi][ni] = mfma16(af[mi], bfr[ni], acc[mi][ni]);
  }

#pragma unroll
  for (int mi = 0; mi < 4; mi++) {
#pragma unroll
    for (int ni = 0; ni < 4; ni++) {
      const int gm0 = tm + wm + mi * 16 + quad * 4;
      const int gn = tn + wn + ni * 16 + ln;
      const float bv_ = bias[gn];
      const int hh = gn >> 6, dd = gn & 63;
      const int b0 = gm0 >> 11, t0 = gm0 & 2047;
      if (z < 2) {
        u16* p = QK + (((size_t)(b0 * Hn + hh) * Tdim) + t0) * HD + dd;
#pragma unroll
        for (int r = 0; r < 4; r++) p[r * HD] = f2bf(acc[mi][ni][r] + bv_);
      } else {
        U16x4 pk;
        pk.x = f2bf(acc[mi][ni][0] + bv_);
        pk.y = f2bf(acc[mi][ni][1] + bv_);
        pk.z = f2bf(acc[mi][ni][2] + bv_);
        pk.w = f2bf(acc[mi][ni][3] + bv_);
        *(U16x4*)&Vt[((size_t)(b0 * Hn + hh) * HD + dd) * Tdim + t0] = pk;
      }
    }
  }
}

// ---------------- flash attention v7: v6 structure at non-spilling occupancy ----------------
// grid (32, 32): qb = 15-(bx>>1) heavy-first, s = bx&1 split-K half.
// (256,3): 170-reg budget (~64 acc + ~100 arch), 3 blocks/CU.
// Staging in two passes of 2x16B to keep live staging regs at 16.
#define KSTR 68
#define VSTR 132
#define L2E 1.44269504088896f
__global__ __launch_bounds__(256, 3) void attn_k(
    const u16* __restrict__ Q, const u16* __restrict__ K, const u16* __restrict__ Vt,
    u16* __restrict__ Op, float* __restrict__ lp) {
  __shared__ alignas(16) u16 Klds[128 * KSTR];
  __shared__ alignas(16) u16 Vtlds[64 * VSTR];

  const int bx = blockIdx.x;
  const int qb = 15 - (bx >> 1);
  const int s = bx & 1;
  const int bh = blockIdx.y;
  const int q0 = qb * 128;
  const int tid = threadIdx.x;
  const int w = tid >> 6, lane = tid & 63;
  const int qi = lane & 31, hf = lane >> 5;

  const u16* Qh = Q + (size_t)bh * Tdim * HD;
  const u16* Kh = K + (size_t)bh * Tdim * HD;
  const u16* Vh = Vt + (size_t)bh * HD * Tdim;
  const float slope = exp2f(-0.5f * (float)((bh & 15) + 1));

  const int nkt = qb + 1;
  const int h0 = (nkt + 1) >> 1;
  const int kt0 = s ? h0 : 0;
  const int kt1 = s ? nkt : h0;

  const int tg = q0 + w * 32 + qi;
  const float sl2 = slope * L2E;
  const float c1 = 0.125f * L2E;
  const float tt2 = (slope * (float)tg + 3.0f) * L2E;
  const float f4hf = (float)(4 * hf);
  float sg8[4], slm[4];
#pragma unroll
  for (int g = 0; g < 4; g++) sg8[g] = sl2 * (float)(8 * g);
#pragma unroll
  for (int m = 0; m < 4; m++) slm[m] = sl2 * (float)m;

  bf16x8 qf[4];
#pragma unroll
  for (int kc = 0; kc < 4; kc++)
    qf[kc] = *(const bf16x8*)&Qh[(size_t)tg * HD + kc * 16 + hf * 8];

  float lsum = 0.f;
  f32x16 oacc[2] = {};

  for (int kt = kt0; kt < kt1; kt++) {
    const int kb = kt * 128;
    __syncthreads();
    // two-pass staging: only 2+2 vectors live at a time
#pragma unroll
    for (int g2 = 0; g2 < 2; g2++) {
      bf16x8 kr[2], vr[2];
#pragma unroll
      for (int c = 0; c < 2; c++) {
        const int e = (g2 * 2 + c) * 2048 + tid * 8;
        kr[c] = *(const bf16x8*)&Kh[(size_t)(kb + (e >> 6)) * HD + (e & 63)];
        vr[c] = *(const bf16x8*)&Vh[(size_t)(e >> 7) * Tdim + kb + (e & 127)];
      }
#pragma unroll
      for (int c = 0; c < 2; c++) {
        const int e = (g2 * 2 + c) * 2048 + tid * 8;
        *(bf16x8*)&Klds[(e >> 6) * KSTR + (e & 63)] = kr[c];
        *(bf16x8*)&Vtlds[(e >> 7) * VSTR + (e & 127)] = vr[c];
      }
    }
    __syncthreads();

    const bool diag = (kt == nkt - 1);
    const float fkb = (float)kb + f4hf;

#pragma unroll
    for (int half = 0; half < 2; half++) {
      // S^T = K Q^T for 64 keys (2 tiles of 32)
      f32x16 st[2] = {};
#pragma unroll
      for (int kc = 0; kc < 4; kc++) {
#pragma unroll
        for (int j = 0; j < 2; j++) {
          bf16x8 kf = *(const bf16x8*)&Klds[(half * 64 + j * 32 + qi) * KSTR + kc * 16 + hf * 8];
          st[j] = mfma32(kf, qf[kc], st[j]);
        }
      }
#pragma unroll
      for (int j = 0; j < 2; j++) {
        const int ni = half * 2 + j;
        const float cni = __builtin_fmaf(sl2, fkb + (float)(32 * ni), -tt2);
        u32 pu[16];
        if (!diag) {
#pragma unroll
          for (int ri = 0; ri < 16; ri++) {
            const float e = __builtin_fmaf(st[j][ri], c1, cni + sg8[ri >> 2] + slm[ri & 3]);
            const float p = __builtin_amdgcn_exp2f(e);
            lsum += p;
            pu[ri] = fbits(p) + 0x8000u;
          }
        } else {
#pragma unroll
          for (int ri = 0; ri < 16; ri++) {
            const int n = kb + ni * 32 + (ri & 3) + 8 * (ri >> 2) + 4 * hf;
            const float e = __builtin_fmaf(st[j][ri], c1, cni + sg8[ri >> 2] + slm[ri & 3]);
            float p = __builtin_amdgcn_exp2f(e);
            if (n > tg) p = 0.f;
            lsum += p;
            pu[ri] = fbits(p) + 0x8000u;
          }
        }
        u32 pk[4][2];
#pragma unroll
        for (int g = 0; g < 4; g++) {
          pk[g][0] = __builtin_amdgcn_perm(pu[g * 4 + 1], pu[g * 4 + 0], 0x07060302u);
          pk[g][1] = __builtin_amdgcn_perm(pu[g * 4 + 3], pu[g * 4 + 2], 0x07060302u);
        }
#pragma unroll
        for (int a = 0; a < 2; a++) {
          const u32 snd0 = (hf == 0) ? pk[2 * a + 1][0] : pk[2 * a][0];
          const u32 snd1 = (hf == 0) ? pk[2 * a + 1][1] : pk[2 * a][1];
          const u32 rcv0 = (u32)__shfl_xor((int)snd0, 32);
          const u32 rcv1 = (u32)__shfl_xor((int)snd1, 32);
          u32x4 fr;
          fr.x = (hf == 0) ? pk[2 * a][0] : rcv0;
          fr.y = (hf == 0) ? pk[2 * a][1] : rcv1;
          fr.z = (hf == 0) ? rcv0 : pk[2 * a + 1][0];
          fr.w = (hf == 0) ? rcv1 : pk[2 * a + 1][1];
          const bf16x8 pfrag = *(bf16x8*)&fr;
          const int kf16 = ni * 2 + a;
#pragma unroll
          for (int nd = 0; nd < 2; nd++) {
            bf16x8 vf = *(const bf16x8*)&Vtlds[(nd * 32 + qi) * VSTR + kf16 * 16 + hf * 8];
            oacc[nd] = mfma32(pfrag, vf, oacc[nd]);
          }
        }
      }
    }
  }

  lsum += __shfl_xor(lsum, 32);
  if (hf == 0) lp[(size_t)s * 65536 + bh * Tdim + tg] = lsum;

  u16* Ob = Op + (size_t)s * OSZ + ((size_t)bh * Tdim) * HD;
#pragma unroll
  for (int nd = 0; nd < 2; nd++) {
#pragma unroll
    for (int ri = 0; ri < 16; ri++) {
      const int rq = (ri & 3) + 8 * (ri >> 2) + 4 * hf;
      const int t = q0 + w * 32 + rq;
      Ob[(size_t)t * HD + nd * 32 + qi] = f2bf(oacc[nd][ri]);
    }
  }
}

// ---------------- output projection GEMM with fused merge (f32 out) ----------------
// A-tile staged on the fly from Op0+Op1 with 1/l normalization.
// 64x128 tiles -> grid (64, 8) = 512 blocks.
__global__ __launch_bounds__(256, 3) void gemm_out(
    const u16* __restrict__ Op, const float* __restrict__ lp,
    const u16* __restrict__ WoT, const float* __restrict__ bo,
    float* __restrict__ C) {
  __shared__ alignas(16) u16 Alds[64 * 32];
  __shared__ alignas(16) u16 Blds[128 * 32];
  const int tid = threadIdx.x;
  const int w = tid >> 6, lane = tid & 63, ln = lane & 15, quad = lane >> 4;
  const int wm = (w >> 1) * 32, wn = (w & 1) * 64;
  const int tm = blockIdx.x * 64, tn = blockIdx.y * 128;

  f32x4 acc[2][4] = {};

  const int srow = tid >> 2, scol = (tid & 3) * 8;
  const int arow = tm + srow;
  const int t = arow & 2047, bb = arow >> 11;
  const u16* bg = WoT + (size_t)(tn + srow) * Ddim + scol;
  const u16* bg2 = bg + (size_t)64 * Ddim;
  u16* bl = &Blds[w * 512];
  u16* bl2 = &Blds[2048 + w * 512];

  for (int k0 = 0; k0 < Ddim; k0 += 32) {
    __syncthreads();
    cp16(bg + k0, bl);
    cp16(bg2 + k0, bl2);
    {
      const int col = k0 + scol;
      const int h = col >> 6, d = col & 63;
      const int bh = bb * 16 + h;
      const float l = lp[bh * Tdim + t] + lp[65536 + bh * Tdim + t];
      const float inv = 1.0f / l;
      const size_t off = ((size_t)bh * Tdim + t) * HD + d;
      U16x8 o0 = *(const U16x8*)&Op[off];
      U16x8 o1 = *(const U16x8*)&Op[OSZ + off];
      u16 tmp[8];
#pragma unroll
      for (int j = 0; j < 8; j++)
        tmp[j] = f2bf((bf2f(o0.s[j]) + bf2f(o1.s[j])) * inv);
      *(bf16x8*)&Alds[srow * 32 + scol] = *(const bf16x8*)tmp;
    }
    __syncthreads();
    bf16x8 af[2], bfr[4];
#pragma unroll
    for (int i = 0; i < 2; i++)
      af[i] = *(const bf16x8*)&Alds[(wm + i * 16 + ln) * 32 + quad * 8];
#pragma unroll
    for (int i = 0; i < 4; i++)
      bfr[i] = *(const bf16x8*)&Blds[(wn + i * 16 + ln) * 32 + quad * 8];
#pragma unroll
    for (int mi = 0; mi < 2; mi++)
#pragma unroll
      for (int ni = 0; ni < 4; ni++)
        acc[mi][ni] = mfma16(af[mi], bfr[ni], acc[mi][ni]);
  }

#pragma unroll
  for (int mi = 0; mi < 2; mi++) {
#pragma unroll
    for (int ni = 0; ni < 4; ni++) {
      const int gm0 = tm + wm + mi * 16 + quad * 4;
      const int gn = tn + wn + ni * 16 + ln;
      const float bv_ = bo[gn];
#pragma unroll
      for (int r = 0; r < 4; r++)
        C[(size_t)(gm0 + r) * Ddim + gn] = acc[mi][ni][r] + bv_;
    }
  }
}

extern "C" void kernel_launch(void* const* d_in, const int* in_sizes, int n_in,
                              void* d_out, int out_size, void* d_ws, size_t ws_size,
                              hipStream_t stream) {
  (void)in_sizes; (void)n_in; (void)out_size; (void)ws_size;
  const float* x  = (const float*)d_in[0];
  const float* Wq = (const float*)d_in[1];
  const float* bq = (const float*)d_in[2];
  const float* Wk = (const float*)d_in[3];
  const float* bk = (const float*)d_in[4];
  const float* Wv = (const float*)d_in[5];
  const float* bv = (const float*)d_in[6];
  const float* Wo = (const float*)d_in[7];
  const float* bo = (const float*)d_in[8];

  char* ws = (char*)d_ws;
  const size_t MB = 1024 * 1024;
  u16* WT   = (u16*)(ws + 0 * MB);   // 8MB: WqT, WkT, WvT, WoT (z-major)
  u16* Qb   = (u16*)(ws + 8 * MB);   // 8MB bf16 (B,H,T,64)
  u16* Kb   = (u16*)(ws + 16 * MB);
  u16* Vtb  = (u16*)(ws + 24 * MB);  // 8MB bf16 (B,H,64,T)
  u16* Xb   = (u16*)(ws + 32 * MB);  // 8MB bf16 X
  u16* Opart= (u16*)(ws + 40 * MB);  // 16MB: 2 x (BH,T,64) bf16 partial O
  float* lpart = (float*)(ws + 56 * MB); // 512KB: 2 x (BH,T) f32 partial l
  u16* WoT = WT + (size_t)3 * Ddim * Ddim;

  convert_x<<<dim3(2048), 256, 0, stream>>>(x, Xb);
  transpose_k<<<dim3(32, 32, 4), dim3(32, 8), 0, stream>>>(Wq, Wk, Wv, Wo, WT);

  gemm_qkv<<<dim3(32, 8, 3), 256, 0, stream>>>(Xb, WT, bq, bk, bv, Qb, Kb, Vtb);
  attn_k<<<dim3(32, 32), 256, 0, stream>>>(Qb, Kb, Vtb, Opart, lpart);
  gemm_out<<<dim3(64, 8), 256, 0, stream>>>(Opart, lpart, WoT, bo, (float*)d_out);
}